// Round 4
// baseline (407.607 us; speedup 1.0000x reference)
//
#include <hip/hip_runtime.h>
#include <math.h>

// Mamba block. GEMMs: pre-converted f16 split-2 operands ([hi|lo] planes),
// m97-style MFMA GEMM with global_load_lds staging. Chunked parallel scan.

typedef _Float16 half8 __attribute__((ext_vector_type(8)));
typedef float floatx4 __attribute__((ext_vector_type(4)));

#define NSTATE 16
#define NCHUNK 32
#define LCHUNK 32

__device__ __forceinline__ void gload_lds16(const _Float16* g, _Float16* l) {
    __builtin_amdgcn_global_load_lds(
        (const __attribute__((address_space(1))) unsigned int*)g,
        (__attribute__((address_space(3))) unsigned int*)l, 16, 0, 0);
}

// ---------- converter: fp32 [R][K] -> f16 [Rpad][2K] = [hi | lo] ----------
__global__ __launch_bounds__(256) void convert_split(
    const float* __restrict__ src, _Float16* __restrict__ dst,
    int R, int Rpad, int K)
{
    int idx = blockIdx.x * 256 + threadIdx.x;    // over Rpad * K/8 chunks
    int nck = K >> 3;
    int r = idx / nck;
    int g = idx - r * nck;
    if (r >= Rpad) return;
    half8 h, l;
    if (r < R) {
        const float* sp = src + (size_t)r * K + g * 8;
        #pragma unroll
        for (int e = 0; e < 8; ++e) {
            float x = sp[e];
            _Float16 hv = (_Float16)x;
            h[e] = hv;
            l[e] = (_Float16)(x - (float)hv);
        }
    } else {
        #pragma unroll
        for (int e = 0; e < 8; ++e) { h[e] = (_Float16)0.f; l[e] = (_Float16)0.f; }
    }
    _Float16* dp = dst + (size_t)r * 2 * K + g * 8;
    *(half8*)dp = h;
    *(half8*)(dp + K) = l;
}

// ---------- MFMA GEMM: C[M,N](fp32) = A2[M,2K](f16 hi|lo) @ W2[Npad,2K]^T ----------
// 128x128 tile, BK=32, 4 waves; wave w DMA-stages tile w (Ah,Al,Wh,Wl).
__global__ __launch_bounds__(256) void hgemm2(
    const _Float16* __restrict__ A2, const _Float16* __restrict__ W2,
    const float* __restrict__ bias, float* __restrict__ C, float* __restrict__ C2,
    int colSplit, int ldc, int Nvalid, int K, int kBegin, int kSteps)
{
    __shared__ _Float16 lds[4 * 128 * 32];   // Ah | Al | Wh | Wl, each [128][32]
    const int tid = threadIdx.x;
    const int lane = tid & 63;
    const int wid = tid >> 6;
    const int wm = wid >> 1, wn = wid & 1;
    const int m0 = blockIdx.y * 128, n0 = blockIdx.x * 128;
    const int kg = lane >> 4, fr = lane & 15;
    const size_t K2 = (size_t)2 * K;

    // staging assignment: wave 0 -> Ah, 1 -> Al, 2 -> Wh, 3 -> Wl
    const bool isA = wid < 2;
    const int limbOff = (wid & 1) ? K : 0;
    const _Float16* gsrc = isA ? A2 + (size_t)m0 * K2 : W2 + (size_t)n0 * K2;
    _Float16* myTile = lds + wid * 4096;
    const int srow = lane >> 2;              // + i*16 per issue
    const int scol = (lane & 3) * 8;
    const _Float16* gp = gsrc + (size_t)srow * K2 + limbOff + kBegin + scol;

    floatx4 acc[4][4];
    #pragma unroll
    for (int mi = 0; mi < 4; ++mi)
        #pragma unroll
        for (int ni = 0; ni < 4; ++ni)
            acc[mi][ni] = (floatx4){0.f, 0.f, 0.f, 0.f};

    const int aoff = (wm * 64 + fr) * 32 + kg * 8;
    const int woff = (wn * 64 + fr) * 32 + kg * 8;

    for (int ks = 0; ks < kSteps; ++ks) {
        const _Float16* gks = gp + ks * 32;
        #pragma unroll
        for (int i = 0; i < 8; ++i)
            gload_lds16(gks + (size_t)i * 16 * K2, myTile + i * 512);
        __syncthreads();

        half8 ah[4], al[4], wh[4], wl[4];
        #pragma unroll
        for (int mi = 0; mi < 4; ++mi) {
            ah[mi] = *(const half8*)(lds + aoff + mi * 512);
            al[mi] = *(const half8*)(lds + 4096 + aoff + mi * 512);
        }
        #pragma unroll
        for (int ni = 0; ni < 4; ++ni) {
            wh[ni] = *(const half8*)(lds + 8192 + woff + ni * 512);
            wl[ni] = *(const half8*)(lds + 12288 + woff + ni * 512);
        }
        #pragma unroll
        for (int mi = 0; mi < 4; ++mi)
            #pragma unroll
            for (int ni = 0; ni < 4; ++ni) {
                acc[mi][ni] = __builtin_amdgcn_mfma_f32_16x16x32_f16(
                    ah[mi], wh[ni], acc[mi][ni], 0, 0, 0);
                acc[mi][ni] = __builtin_amdgcn_mfma_f32_16x16x32_f16(
                    ah[mi], wl[ni], acc[mi][ni], 0, 0, 0);
                acc[mi][ni] = __builtin_amdgcn_mfma_f32_16x16x32_f16(
                    al[mi], wh[ni], acc[mi][ni], 0, 0, 0);
            }
        __syncthreads();
    }

    // epilogue: col = lane&15 (fr), row-in-frag = kg*4 + r
    #pragma unroll
    for (int ni = 0; ni < 4; ++ni) {
        int nn = n0 + wn * 64 + ni * 16 + fr;
        if (nn >= Nvalid) continue;
        float bv = bias ? bias[nn] : 0.f;
        float* Cp = C;
        int col = nn;
        if (C2 && nn >= colSplit) { Cp = C2; col = nn - colSplit; }
        #pragma unroll
        for (int mi = 0; mi < 4; ++mi) {
            int mm = m0 + wm * 64 + mi * 16 + kg * 4;
            float* p = Cp + (size_t)mm * ldc + col;
            #pragma unroll
            for (int r = 0; r < 4; ++r)
                p[(size_t)r * ldc] = acc[mi][ni][r] + bv;
        }
    }
}

// ---------- conv + silu, emits f16 [hi|lo] layout (width 2*2048) ----------
__global__ __launch_bounds__(256) void conv_silu2(
    const float* __restrict__ xc, const float* __restrict__ conv_w,
    const float* __restrict__ conv_b, _Float16* __restrict__ xcs2)
{
    const int D = 2048, L = 1024;
    int idx = blockIdx.x * 256 + threadIdx.x;   // (b,l,g) g in 0..255
    int g = idx & 255;
    int l = (idx >> 8) & (L - 1);
    int b = idx >> 18;
    int d0 = g * 8;
    int row = b * L + l;

    float a[8];
    #pragma unroll
    for (int j = 0; j < 8; ++j) a[j] = conv_b[d0 + j];
    #pragma unroll
    for (int t = 0; t < 4; ++t) {
        int lt = l - 3 + t;
        if (lt >= 0) {
            const float* rp = xc + (size_t)(b * L + lt) * D + d0;
            #pragma unroll
            for (int j = 0; j < 8; ++j)
                a[j] = fmaf(rp[j], conv_w[(d0 + j) * 4 + t], a[j]);
        }
    }
    half8 h, lo;
    #pragma unroll
    for (int j = 0; j < 8; ++j) {
        float v = a[j];
        float s = v / (1.f + expf(-v));
        _Float16 hv = (_Float16)s;
        h[j] = hv;
        lo[j] = (_Float16)(s - (float)hv);
    }
    _Float16* dp = xcs2 + (size_t)row * 4096 + d0;
    *(half8*)dp = h;
    *(half8*)(dp + 2048) = lo;
}

__device__ __forceinline__ float softplusf(float x) {
    return (x > 20.f) ? x : log1pf(expf(x));
}

// ---------- chunked scan ----------
__global__ __launch_bounds__(256) void scan_pass1(
    const float* __restrict__ dbu, const float* __restrict__ W_dt,
    const float* __restrict__ b_dt, const float* __restrict__ A_log,
    float* __restrict__ Sout, float* __restrict__ Pout)
{
    const int D = 2048, L = 1024, NDBU = 2080;
    const int g = blockIdx.x & 7;
    const int c = (blockIdx.x >> 3) & (NCHUNK - 1);
    const int b = blockIdx.x >> 8;
    const int d = g * 256 + threadIdx.x;

    float wdt[NSTATE], Aneg[NSTATE], s[NSTATE], P[NSTATE];
    #pragma unroll
    for (int n = 0; n < NSTATE; ++n) {
        wdt[n] = W_dt[d * NSTATE + n];
        Aneg[n] = -expf(A_log[d * NSTATE + n]);
        s[n] = 0.f; P[n] = 1.f;
    }
    const float bdt = b_dt[d];

    __shared__ float sbuf[LCHUNK][33];
    {
        int r = threadIdx.x >> 3;
        int c4 = (threadIdx.x & 7) * 4;
        float4 v = *(const float4*)(dbu + ((size_t)b * L + c * LCHUNK + r) * NDBU + c4);
        sbuf[r][c4 + 0] = v.x; sbuf[r][c4 + 1] = v.y;
        sbuf[r][c4 + 2] = v.z; sbuf[r][c4 + 3] = v.w;
    }
    __syncthreads();

    for (int li = 0; li < LCHUNK; ++li) {
        const int l = c * LCHUNK + li;
        const float u = dbu[((size_t)b * L + l) * NDBU + 32 + d];
        float accd = bdt;
        #pragma unroll
        for (int n = 0; n < NSTATE; ++n) accd = fmaf(sbuf[li][n], wdt[n], accd);
        const float delta = softplusf(accd);
        const float du = delta * u;
        #pragma unroll
        for (int n = 0; n < NSTATE; ++n) {
            float dA = expf(delta * Aneg[n]);
            s[n] = fmaf(dA, s[n], du * sbuf[li][16 + n]);
            P[n] *= dA;
        }
    }
    const size_t o = (((size_t)b * NCHUNK + c) * D + d) * NSTATE;
    #pragma unroll
    for (int n = 0; n < NSTATE; ++n) { Sout[o + n] = s[n]; Pout[o + n] = P[n]; }
}

__global__ __launch_bounds__(256) void scan_mid(
    const float* __restrict__ S, float* __restrict__ P)
{
    const int D = 2048;
    int idx = blockIdx.x * 256 + threadIdx.x;
    int n = idx & 15;
    int d = (idx >> 4) & (D - 1);
    int b = idx >> 15;
    float carry = 0.f;
    for (int c = 0; c < NCHUNK; ++c) {
        size_t o = (((size_t)b * NCHUNK + c) * D + d) * NSTATE + n;
        float Sv = S[o], Pv = P[o];
        P[o] = carry;
        carry = fmaf(Pv, carry, Sv);
    }
}

// pass2: local scan with carry-in; y gated, emitted as f16 [hi|lo] (width 4096)
__global__ __launch_bounds__(256) void scan_pass2(
    const float* __restrict__ dbu, const float* __restrict__ z,
    const float* __restrict__ W_dt, const float* __restrict__ b_dt,
    const float* __restrict__ A_log, const float* __restrict__ Dp,
    const float* __restrict__ CarryIn, _Float16* __restrict__ y2)
{
    const int D = 2048, L = 1024, NDBU = 2080;
    const int g = blockIdx.x & 7;
    const int c = (blockIdx.x >> 3) & (NCHUNK - 1);
    const int b = blockIdx.x >> 8;
    const int d = g * 256 + threadIdx.x;

    float wdt[NSTATE], Aneg[NSTATE], s[NSTATE];
    const size_t o = (((size_t)b * NCHUNK + c) * D + d) * NSTATE;
    #pragma unroll
    for (int n = 0; n < NSTATE; ++n) {
        wdt[n] = W_dt[d * NSTATE + n];
        Aneg[n] = -expf(A_log[d * NSTATE + n]);
        s[n] = CarryIn[o + n];
    }
    const float bdt = b_dt[d];
    const float dp = Dp[d];

    __shared__ float sbuf[LCHUNK][33];
    {
        int r = threadIdx.x >> 3;
        int c4 = (threadIdx.x & 7) * 4;
        float4 v = *(const float4*)(dbu + ((size_t)b * L + c * LCHUNK + r) * NDBU + c4);
        sbuf[r][c4 + 0] = v.x; sbuf[r][c4 + 1] = v.y;
        sbuf[r][c4 + 2] = v.z; sbuf[r][c4 + 3] = v.w;
    }
    __syncthreads();

    for (int li = 0; li < LCHUNK; ++li) {
        const int l = c * LCHUNK + li;
        const int row = b * L + l;
        const float u = dbu[(size_t)row * NDBU + 32 + d];
        float accd = bdt;
        #pragma unroll
        for (int n = 0; n < NSTATE; ++n) accd = fmaf(sbuf[li][n], wdt[n], accd);
        const float delta = softplusf(accd);
        const float du = delta * u;
        float sum = 0.f;
        #pragma unroll
        for (int n = 0; n < NSTATE; ++n) {
            float dA = expf(delta * Aneg[n]);
            s[n] = fmaf(dA, s[n], du * sbuf[li][16 + n]);
            sum += s[n];
        }
        const float zz = z[(size_t)row * D + d];
        const float yv = (sum + u) * dp * (zz / (1.f + expf(-zz)));
        _Float16 hv = (_Float16)yv;
        y2[(size_t)row * 4096 + d] = hv;
        y2[(size_t)row * 4096 + 2048 + d] = (_Float16)(yv - (float)hv);
    }
}

// ---------- combine split-K partials + bias ----------
__global__ __launch_bounds__(256) void combine2(
    const float* __restrict__ p1, const float* __restrict__ p2,
    const float* __restrict__ bias, float* __restrict__ out)
{
    int i = (blockIdx.x * 256 + threadIdx.x) * 4;   // over 2048*1024
    int n = i & 1023;
    float4 a = *(const float4*)(p1 + i);
    float4 b = *(const float4*)(p2 + i);
    float4 bb = *(const float4*)(bias + n);
    float4 r;
    r.x = a.x + b.x + bb.x; r.y = a.y + b.y + bb.y;
    r.z = a.z + b.z + bb.z; r.w = a.w + b.w + bb.w;
    *(float4*)(out + i) = r;
}

extern "C" void kernel_launch(void* const* d_in, const int* in_sizes, int n_in,
                              void* d_out, int out_size, void* d_ws, size_t ws_size,
                              hipStream_t stream) {
    const float* x      = (const float*)d_in[0];
    const float* W_in   = (const float*)d_in[1];
    const float* b_in   = (const float*)d_in[2];
    const float* conv_w = (const float*)d_in[3];
    const float* conv_b = (const float*)d_in[4];
    const float* W_x    = (const float*)d_in[5];
    const float* b_x    = (const float*)d_in[6];
    const float* W_dt   = (const float*)d_in[7];
    const float* b_dt   = (const float*)d_in[8];
    const float* A_log  = (const float*)d_in[9];
    const float* Dp     = (const float*)d_in[10];
    const float* W_out  = (const float*)d_in[11];
    const float* b_out  = (const float*)d_in[12];
    float* out = (float*)d_out;

    // ws regions (bytes):
    //  z    @ 0         : fp32 2048x2048                (16,777,216)
    //  xc/dbu @16777216 : fp32 2048x2048 then 2048x2080 (17,039,360)
    //  big  @33816576   : f16  16,777,216 B  {Win2 | xcs2 | y2}
    //  aux  @50593792   : 17,825,792 B       {xh2 | Wx2 | S | partials}
    //  misc @68419584   : 8,388,608 B        {P | Wout2}
    char* ws = (char*)d_ws;
    float*    z     = (float*)(ws);
    float*    xc    = (float*)(ws + 16777216);
    float*    dbu   = xc;
    _Float16* big   = (_Float16*)(ws + 33816576);
    _Float16* aux   = (_Float16*)(ws + 50593792);
    _Float16* misc  = (_Float16*)(ws + 68419584);

    _Float16* Win2  = big;                 // [4096][2048]
    _Float16* xh2   = aux;                 // [2048][2048]
    _Float16* xcs2  = big;                 // [2048][4096]
    _Float16* Wx2   = aux;                 // [2176][4096]
    float*    Sb    = (float*)aux;         // 2*32*2048*16
    float*    Pb    = (float*)misc;
    _Float16* y2    = big;                 // [2048][4096]
    _Float16* Wout2 = misc;                // [1024][4096]
    float*    part1 = (float*)aux;         // [2048][1024]
    float*    part2 = part1 + (size_t)2048 * 1024;

    dim3 blk(256);

    // converters for GEMM1
    convert_split<<<1024, blk, 0, stream>>>(x, xh2, 2048, 2048, 1024);
    convert_split<<<2048, blk, 0, stream>>>(W_in, Win2, 4096, 4096, 1024);

    // GEMM1: xz = x @ W_in.T + b_in -> xc (cols<2048) and z (cols>=2048)
    hgemm2<<<dim3(32, 16), blk, 0, stream>>>(
        xh2, Win2, b_in, xc, z, 2048, 2048, 4096, 1024, 0, 32);

    // conv + silu -> xcs2 (f16 hi|lo)
    conv_silu2<<<2048, blk, 0, stream>>>(xc, conv_w, conv_b, xcs2);

    // GEMM2: dbu = xcs @ W_x.T + b_x
    convert_split<<<2176, blk, 0, stream>>>(W_x, Wx2, 2080, 2176, 2048);
    hgemm2<<<dim3(17, 16), blk, 0, stream>>>(
        xcs2, Wx2, b_x, dbu, (float*)nullptr, 1 << 30, 2080, 2080, 2048, 0, 64);

    // chunked scan -> y2 (f16 hi|lo)
    scan_pass1<<<2 * NCHUNK * 8, blk, 0, stream>>>(dbu, W_dt, b_dt, A_log, Sb, Pb);
    scan_mid<<<(2 * 2048 * NSTATE) / 256, blk, 0, stream>>>(Sb, Pb);
    scan_pass2<<<2 * NCHUNK * 8, blk, 0, stream>>>(dbu, z, W_dt, b_dt, A_log, Dp, Pb, y2);

    // GEMM3 (split-K=2): out = y @ W_out.T + b_out
    convert_split<<<1024, blk, 0, stream>>>(W_out, Wout2, 1024, 1024, 2048);
    hgemm2<<<dim3(8, 16), blk, 0, stream>>>(
        y2, Wout2, (const float*)nullptr, part1, (float*)nullptr, 1 << 30, 1024, 1024, 2048, 0, 32);
    hgemm2<<<dim3(8, 16), blk, 0, stream>>>(
        y2, Wout2, (const float*)nullptr, part2, (float*)nullptr, 1 << 30, 1024, 1024, 2048, 1024, 32);
    combine2<<<2048, blk, 0, stream>>>(part1, part2, b_out, out);
}

// Round 5
// 342.231 us; speedup vs baseline: 1.1910x; 1.1910x over previous
//
#include <hip/hip_runtime.h>
#include <math.h>

// Mamba block. GEMMs: pre-converted f16 split-2 operands ([hi|lo] planes),
// double-buffered global_load_lds prefetch, XOR bank swizzle, XCD block swizzle.
// Chunked parallel scan.

typedef _Float16 half8 __attribute__((ext_vector_type(8)));
typedef float floatx4 __attribute__((ext_vector_type(4)));

#define NSTATE 16
#define NCHUNK 32
#define LCHUNK 32

__device__ __forceinline__ void gload_lds16(const _Float16* g, _Float16* l) {
    __builtin_amdgcn_global_load_lds(
        (const __attribute__((address_space(1))) unsigned int*)g,
        (__attribute__((address_space(3))) unsigned int*)l, 16, 0, 0);
}

// ---------- converter: fp32 [R][K] -> f16 [Rpad][2K] = [hi | lo] ----------
__global__ __launch_bounds__(256) void convert_split(
    const float* __restrict__ src, _Float16* __restrict__ dst,
    int R, int Rpad, int K)
{
    int idx = blockIdx.x * 256 + threadIdx.x;    // over Rpad * K/8 chunks
    int nck = K >> 3;
    int r = idx / nck;
    int g = idx - r * nck;
    if (r >= Rpad) return;
    half8 h, l;
    if (r < R) {
        const float* sp = src + (size_t)r * K + g * 8;
        #pragma unroll
        for (int e = 0; e < 8; ++e) {
            float x = sp[e];
            _Float16 hv = (_Float16)x;
            h[e] = hv;
            l[e] = (_Float16)(x - (float)hv);
        }
    } else {
        #pragma unroll
        for (int e = 0; e < 8; ++e) { h[e] = (_Float16)0.f; l[e] = (_Float16)0.f; }
    }
    _Float16* dp = dst + (size_t)r * 2 * K + g * 8;
    *(half8*)dp = h;
    *(half8*)(dp + K) = l;
}

// ---------- MFMA GEMM: C[M,N](fp32) = A2[M,2K](f16 hi|lo) @ W2[Npad,2K]^T ----------
// 128x128 tile, BK=32, 4 waves; wave w DMA-stages tile w (Ah,Al,Wh,Wl).
// Double-buffered LDS prefetch; XOR chunk swizzle; XCD-chunked block swizzle.
__global__ __launch_bounds__(256) void hgemm2(
    const _Float16* __restrict__ A2, const _Float16* __restrict__ W2,
    const float* __restrict__ bias, float* __restrict__ C, float* __restrict__ C2,
    int colSplit, int ldc, int Nvalid, int K, int kSteps,
    int kzStride, size_t zStrideC)
{
    __shared__ _Float16 lds[2 * 4 * 128 * 32];   // 2 bufs x {Ah|Al|Wh|Wl}[128][32]

    // XCD-chunked swizzle (nwg % 8 == 0, gridDim.y == 16)
    const int nbx = gridDim.x;
    const int h = blockIdx.y * nbx + blockIdx.x;       // HW dispatch order (x fastest)
    const int cpx = (nbx * 16) >> 3;
    const int e = (h & 7) * cpx + (h >> 3);            // col-major enum: same-x adjacent
    const int bx = e >> 4, by = e & 15;

    const int tid = threadIdx.x;
    const int lane = tid & 63;
    const int wid = tid >> 6;
    const int wm = wid >> 1, wn = wid & 1;
    const int m0 = by * 128, n0 = bx * 128;
    const int kg = lane >> 4, fr = lane & 15;
    const size_t K2 = (size_t)2 * K;
    const int kBegin = blockIdx.z * kzStride;

    // staging: wave 0 -> Ah, 1 -> Al, 2 -> Wh, 3 -> Wl
    const bool isA = wid < 2;
    const int limbOff = (wid & 1) ? K : 0;
    const _Float16* gsrc = isA ? A2 + (size_t)m0 * K2 : W2 + (size_t)n0 * K2;
    const int srow = lane >> 2;
    const int scol = (((lane & 3) ^ ((lane >> 3) & 3)) << 3);  // swizzled source chunk
    const _Float16* gp = gsrc + (size_t)srow * K2 + limbOff + kBegin + scol;

    floatx4 acc[4][4];
    #pragma unroll
    for (int mi = 0; mi < 4; ++mi)
        #pragma unroll
        for (int ni = 0; ni < 4; ++ni)
            acc[mi][ni] = (floatx4){0.f, 0.f, 0.f, 0.f};

    const int rsw = (fr >> 1) & 3;                      // read-side swizzle
    const int aoff = (wm * 64 + fr) * 32 + ((kg ^ rsw) << 3);
    const int woff = (wn * 64 + fr) * 32 + ((kg ^ rsw) << 3);

    // prologue: stage tile 0 into buf 0
    {
        _Float16* t = lds + wid * 4096;
        #pragma unroll
        for (int i = 0; i < 8; ++i)
            gload_lds16(gp + (size_t)i * 16 * K2, t + i * 512);
    }

    int cur = 0;
    for (int ks = 0; ks < kSteps; ++ks) {
        __syncthreads();                  // drains vmcnt -> buf[cur] ready
        if (ks + 1 < kSteps) {            // prefetch next tile into other buffer
            const _Float16* gks = gp + (ks + 1) * 32;
            _Float16* t = lds + (cur ^ 1) * 16384 + wid * 4096;
            #pragma unroll
            for (int i = 0; i < 8; ++i)
                gload_lds16(gks + (size_t)i * 16 * K2, t + i * 512);
        }
        const _Float16* buf = lds + cur * 16384;
        half8 ah[4], al[4], wh[4], wl[4];
        #pragma unroll
        for (int mi = 0; mi < 4; ++mi) {
            ah[mi] = *(const half8*)(buf + aoff + mi * 512);
            al[mi] = *(const half8*)(buf + 4096 + aoff + mi * 512);
        }
        #pragma unroll
        for (int ni = 0; ni < 4; ++ni) {
            wh[ni] = *(const half8*)(buf + 8192 + woff + ni * 512);
            wl[ni] = *(const half8*)(buf + 12288 + woff + ni * 512);
        }
        #pragma unroll
        for (int mi = 0; mi < 4; ++mi)
            #pragma unroll
            for (int ni = 0; ni < 4; ++ni) {
                acc[mi][ni] = __builtin_amdgcn_mfma_f32_16x16x32_f16(
                    ah[mi], wh[ni], acc[mi][ni], 0, 0, 0);
                acc[mi][ni] = __builtin_amdgcn_mfma_f32_16x16x32_f16(
                    ah[mi], wl[ni], acc[mi][ni], 0, 0, 0);
                acc[mi][ni] = __builtin_amdgcn_mfma_f32_16x16x32_f16(
                    al[mi], wh[ni], acc[mi][ni], 0, 0, 0);
            }
        cur ^= 1;
    }

    // epilogue: col = fr, row-in-frag = kg*4 + r
    float* Cz  = C  + blockIdx.z * zStrideC;
    float* C2z = C2;
    #pragma unroll
    for (int ni = 0; ni < 4; ++ni) {
        int nn = n0 + wn * 64 + ni * 16 + fr;
        if (nn >= Nvalid) continue;
        float bv = bias ? bias[nn] : 0.f;
        float* Cp = Cz;
        int col = nn;
        if (C2z && nn >= colSplit) { Cp = C2z; col = nn - colSplit; }
        #pragma unroll
        for (int mi = 0; mi < 4; ++mi) {
            int mm = m0 + wm * 64 + mi * 16 + kg * 4;
            float* p = Cp + (size_t)mm * ldc + col;
            #pragma unroll
            for (int r = 0; r < 4; ++r)
                p[(size_t)r * ldc] = acc[mi][ni][r] + bv;
        }
    }
}

// ---------- conv + silu, emits f16 [hi|lo] layout (width 2*2048) ----------
__global__ __launch_bounds__(256) void conv_silu2(
    const float* __restrict__ xc, const float* __restrict__ conv_w,
    const float* __restrict__ conv_b, _Float16* __restrict__ xcs2)
{
    const int D = 2048, L = 1024;
    int idx = blockIdx.x * 256 + threadIdx.x;
    int g = idx & 255;
    int l = (idx >> 8) & (L - 1);
    int b = idx >> 18;
    int d0 = g * 8;
    int row = b * L + l;

    float a[8];
    #pragma unroll
    for (int j = 0; j < 8; ++j) a[j] = conv_b[d0 + j];
    #pragma unroll
    for (int t = 0; t < 4; ++t) {
        int lt = l - 3 + t;
        if (lt >= 0) {
            const float* rp = xc + (size_t)(b * L + lt) * D + d0;
            #pragma unroll
            for (int j = 0; j < 8; ++j)
                a[j] = fmaf(rp[j], conv_w[(d0 + j) * 4 + t], a[j]);
        }
    }
    half8 h, lo;
    #pragma unroll
    for (int j = 0; j < 8; ++j) {
        float v = a[j];
        float s = v / (1.f + expf(-v));
        _Float16 hv = (_Float16)s;
        h[j] = hv;
        lo[j] = (_Float16)(s - (float)hv);
    }
    _Float16* dp = xcs2 + (size_t)row * 4096 + d0;
    *(half8*)dp = h;
    *(half8*)(dp + 2048) = lo;
}

__device__ __forceinline__ float softplusf(float x) {
    return (x > 20.f) ? x : log1pf(expf(x));
}

// ---------- chunked scan ----------
__global__ __launch_bounds__(256) void scan_pass1(
    const float* __restrict__ dbu, const float* __restrict__ W_dt,
    const float* __restrict__ b_dt, const float* __restrict__ A_log,
    float* __restrict__ Sout, float* __restrict__ Pout)
{
    const int D = 2048, L = 1024, NDBU = 2080;
    const int g = blockIdx.x & 7;
    const int c = (blockIdx.x >> 3) & (NCHUNK - 1);
    const int b = blockIdx.x >> 8;
    const int d = g * 256 + threadIdx.x;

    float wdt[NSTATE], Aneg[NSTATE], s[NSTATE], P[NSTATE];
    #pragma unroll
    for (int n = 0; n < NSTATE; ++n) {
        wdt[n] = W_dt[d * NSTATE + n];
        Aneg[n] = -expf(A_log[d * NSTATE + n]);
        s[n] = 0.f; P[n] = 1.f;
    }
    const float bdt = b_dt[d];

    __shared__ float sbuf[LCHUNK][33];
    {
        int r = threadIdx.x >> 3;
        int c4 = (threadIdx.x & 7) * 4;
        float4 v = *(const float4*)(dbu + ((size_t)b * L + c * LCHUNK + r) * NDBU + c4);
        sbuf[r][c4 + 0] = v.x; sbuf[r][c4 + 1] = v.y;
        sbuf[r][c4 + 2] = v.z; sbuf[r][c4 + 3] = v.w;
    }
    __syncthreads();

    for (int li = 0; li < LCHUNK; ++li) {
        const int l = c * LCHUNK + li;
        const float u = dbu[((size_t)b * L + l) * NDBU + 32 + d];
        float accd = bdt;
        #pragma unroll
        for (int n = 0; n < NSTATE; ++n) accd = fmaf(sbuf[li][n], wdt[n], accd);
        const float delta = softplusf(accd);
        const float du = delta * u;
        #pragma unroll
        for (int n = 0; n < NSTATE; ++n) {
            float dA = expf(delta * Aneg[n]);
            s[n] = fmaf(dA, s[n], du * sbuf[li][16 + n]);
            P[n] *= dA;
        }
    }
    const size_t o = (((size_t)b * NCHUNK + c) * D + d) * NSTATE;
    #pragma unroll
    for (int n = 0; n < NSTATE; ++n) { Sout[o + n] = s[n]; Pout[o + n] = P[n]; }
}

__global__ __launch_bounds__(256) void scan_mid(
    const float* __restrict__ S, float* __restrict__ P)
{
    const int D = 2048;
    int idx = blockIdx.x * 256 + threadIdx.x;
    int n = idx & 15;
    int d = (idx >> 4) & (D - 1);
    int b = idx >> 15;
    float carry = 0.f;
    for (int c = 0; c < NCHUNK; ++c) {
        size_t o = (((size_t)b * NCHUNK + c) * D + d) * NSTATE + n;
        float Sv = S[o], Pv = P[o];
        P[o] = carry;
        carry = fmaf(Pv, carry, Sv);
    }
}

__global__ __launch_bounds__(256) void scan_pass2(
    const float* __restrict__ dbu, const float* __restrict__ z,
    const float* __restrict__ W_dt, const float* __restrict__ b_dt,
    const float* __restrict__ A_log, const float* __restrict__ Dp,
    const float* __restrict__ CarryIn, _Float16* __restrict__ y2)
{
    const int D = 2048, L = 1024, NDBU = 2080;
    const int g = blockIdx.x & 7;
    const int c = (blockIdx.x >> 3) & (NCHUNK - 1);
    const int b = blockIdx.x >> 8;
    const int d = g * 256 + threadIdx.x;

    float wdt[NSTATE], Aneg[NSTATE], s[NSTATE];
    const size_t o = (((size_t)b * NCHUNK + c) * D + d) * NSTATE;
    #pragma unroll
    for (int n = 0; n < NSTATE; ++n) {
        wdt[n] = W_dt[d * NSTATE + n];
        Aneg[n] = -expf(A_log[d * NSTATE + n]);
        s[n] = CarryIn[o + n];
    }
    const float bdt = b_dt[d];
    const float dp = Dp[d];

    __shared__ float sbuf[LCHUNK][33];
    {
        int r = threadIdx.x >> 3;
        int c4 = (threadIdx.x & 7) * 4;
        float4 v = *(const float4*)(dbu + ((size_t)b * L + c * LCHUNK + r) * NDBU + c4);
        sbuf[r][c4 + 0] = v.x; sbuf[r][c4 + 1] = v.y;
        sbuf[r][c4 + 2] = v.z; sbuf[r][c4 + 3] = v.w;
    }
    __syncthreads();

    for (int li = 0; li < LCHUNK; ++li) {
        const int l = c * LCHUNK + li;
        const int row = b * L + l;
        const float u = dbu[(size_t)row * NDBU + 32 + d];
        float accd = bdt;
        #pragma unroll
        for (int n = 0; n < NSTATE; ++n) accd = fmaf(sbuf[li][n], wdt[n], accd);
        const float delta = softplusf(accd);
        const float du = delta * u;
        float sum = 0.f;
        #pragma unroll
        for (int n = 0; n < NSTATE; ++n) {
            float dA = expf(delta * Aneg[n]);
            s[n] = fmaf(dA, s[n], du * sbuf[li][16 + n]);
            sum += s[n];
        }
        const float zz = z[(size_t)row * D + d];
        const float yv = (sum + u) * dp * (zz / (1.f + expf(-zz)));
        _Float16 hv = (_Float16)yv;
        y2[(size_t)row * 4096 + d] = hv;
        y2[(size_t)row * 4096 + 2048 + d] = (_Float16)(yv - (float)hv);
    }
}

// ---------- combine split-K partials + bias ----------
__global__ __launch_bounds__(256) void combine2(
    const float* __restrict__ p1, const float* __restrict__ p2,
    const float* __restrict__ bias, float* __restrict__ out)
{
    int i = (blockIdx.x * 256 + threadIdx.x) * 4;   // over 2048*1024
    int n = i & 1023;
    float4 a = *(const float4*)(p1 + i);
    float4 b = *(const float4*)(p2 + i);
    float4 bb = *(const float4*)(bias + n);
    float4 r;
    r.x = a.x + b.x + bb.x; r.y = a.y + b.y + bb.y;
    r.z = a.z + b.z + bb.z; r.w = a.w + b.w + bb.w;
    *(float4*)(out + i) = r;
}

extern "C" void kernel_launch(void* const* d_in, const int* in_sizes, int n_in,
                              void* d_out, int out_size, void* d_ws, size_t ws_size,
                              hipStream_t stream) {
    const float* x      = (const float*)d_in[0];
    const float* W_in   = (const float*)d_in[1];
    const float* b_in   = (const float*)d_in[2];
    const float* conv_w = (const float*)d_in[3];
    const float* conv_b = (const float*)d_in[4];
    const float* W_x    = (const float*)d_in[5];
    const float* b_x    = (const float*)d_in[6];
    const float* W_dt   = (const float*)d_in[7];
    const float* b_dt   = (const float*)d_in[8];
    const float* A_log  = (const float*)d_in[9];
    const float* Dp     = (const float*)d_in[10];
    const float* W_out  = (const float*)d_in[11];
    const float* b_out  = (const float*)d_in[12];
    float* out = (float*)d_out;

    // ws regions (bytes):
    //  z    @ 0         : fp32 2048x2048                (16,777,216)
    //  xc/dbu @16777216 : fp32 2048x2048 then 2048x2080 (17,039,360)
    //  big  @33816576   : f16  16,777,216 B  {Win2 | xcs2 | y2}
    //  aux  @50593792   : 17,825,792 B       {xh2 | Wx2 | S | partials}
    //  misc @68419584   : 8,388,608 B        {P | Wout2}
    char* ws = (char*)d_ws;
    float*    z     = (float*)(ws);
    float*    xc    = (float*)(ws + 16777216);
    float*    dbu   = xc;
    _Float16* big   = (_Float16*)(ws + 33816576);
    _Float16* aux   = (_Float16*)(ws + 50593792);
    _Float16* misc  = (_Float16*)(ws + 68419584);

    _Float16* Win2  = big;                 // [4096][2048]
    _Float16* xh2   = aux;                 // [2048][2048]
    _Float16* xcs2  = big;                 // [2048][4096]
    _Float16* Wx2   = aux;                 // [2176][4096]
    float*    Sb    = (float*)aux;         // 2*32*2048*16
    float*    Pb    = (float*)misc;
    _Float16* y2    = big;                 // [2048][4096]
    _Float16* Wout2 = misc;                // [1024][4096]
    float*    part1 = (float*)aux;         // [2048][1024]
    float*    part2 = part1 + (size_t)2048 * 1024;

    dim3 blk(256);

    // converters for GEMM1
    convert_split<<<1024, blk, 0, stream>>>(x, xh2, 2048, 2048, 1024);
    convert_split<<<2048, blk, 0, stream>>>(W_in, Win2, 4096, 4096, 1024);

    // GEMM1: xz = x @ W_in.T + b_in -> xc (cols<2048) and z (cols>=2048)
    hgemm2<<<dim3(32, 16, 1), blk, 0, stream>>>(
        xh2, Win2, b_in, xc, z, 2048, 2048, 4096, 1024, 32, 0, 0);

    // conv + silu -> xcs2 (f16 hi|lo)
    conv_silu2<<<2048, blk, 0, stream>>>(xc, conv_w, conv_b, xcs2);

    // GEMM2: dbu = xcs @ W_x.T + b_x
    convert_split<<<2176, blk, 0, stream>>>(W_x, Wx2, 2080, 2176, 2048);
    hgemm2<<<dim3(17, 16, 1), blk, 0, stream>>>(
        xcs2, Wx2, b_x, dbu, (float*)nullptr, 1 << 30, 2080, 2080, 2048, 64, 0, 0);

    // chunked scan -> y2 (f16 hi|lo)
    scan_pass1<<<2 * NCHUNK * 8, blk, 0, stream>>>(dbu, W_dt, b_dt, A_log, Sb, Pb);
    scan_mid<<<(2 * 2048 * NSTATE) / 256, blk, 0, stream>>>(Sb, Pb);
    scan_pass2<<<2 * NCHUNK * 8, blk, 0, stream>>>(dbu, z, W_dt, b_dt, A_log, Dp, Pb, y2);

    // GEMM3 (split-K=2, one launch): out = y @ W_out.T + b_out
    convert_split<<<1024, blk, 0, stream>>>(W_out, Wout2, 1024, 1024, 2048);
    hgemm2<<<dim3(8, 16, 2), blk, 0, stream>>>(
        y2, Wout2, (const float*)nullptr, part1, (float*)nullptr, 1 << 30,
        1024, 1024, 2048, 32, 1024, (size_t)2048 * 1024);
    combine2<<<2048, blk, 0, stream>>>(part1, part2, b_out, out);
}